// Round 5
// baseline (1324.081 us; speedup 1.0000x reference)
//
#include <hip/hip_runtime.h>

// GQA forward: gather -> wconv(bf16) -> fused QKV proj -> flash attn -> out proj.
// R5 DIAGNOSTIC: R3 structure (double-buffered global_load_lds, 1-ahead, counted
// vmcnt) with REP-loop templates on the three heavy kernels so each dispatch
// exceeds the ~150us harness fills and surfaces in rocprof top-5 with counters.
// Attention adds s_setprio around MFMA clusters (T5).
// ws (ushort elems): e[4M] Kb[1M] VbT[1M] Qb[4M] Ctx[4M] Wkb[1M] Wvb[1M] Wqb[4M] Wob[4M].

typedef __bf16 bf16x8 __attribute__((ext_vector_type(8)));
typedef float f32x4 __attribute__((ext_vector_type(4)));
typedef float f32x16 __attribute__((ext_vector_type(16)));
typedef unsigned short ushort8_t __attribute__((ext_vector_type(8)));
typedef unsigned int uint4_t __attribute__((ext_vector_type(4)));

#define DEVI static __device__ __forceinline__

DEVI unsigned short f2bf(float f) {
    union { float f; unsigned int u; } c; c.f = f;
    unsigned int u = c.u;
    unsigned int r = (u + 0x7FFFu + ((u >> 16) & 1u)) >> 16;  // RNE
    return (unsigned short)r;
}

DEVI f32x4 mfma16(bf16x8 a, bf16x8 b, f32x4 c) {
    return __builtin_amdgcn_mfma_f32_16x16x32_bf16(a, b, c, 0, 0, 0);
}
DEVI f32x16 mfma32(bf16x8 a, bf16x8 b, f32x16 c) {
    return __builtin_amdgcn_mfma_f32_32x32x16_bf16(a, b, c, 0, 0, 0);
}
DEVI unsigned cvtpk(float a, float b) {
    unsigned r;
    asm("v_cvt_pk_bf16_f32 %0, %1, %2" : "=v"(r) : "v"(a), "v"(b));
    return r;
}
DEVI void plswap(unsigned& a, unsigned& b) {
    asm("v_permlane32_swap_b32 %0, %1" : "+v"(a), "+v"(b));
}
DEVI void gload16(const unsigned short* g, unsigned short* l) {
    __builtin_amdgcn_global_load_lds(
        (const __attribute__((address_space(1))) void*)g,
        (__attribute__((address_space(3))) void*)l, 16, 0, 0);
}
#define WAIT_VM(n) asm volatile("s_waitcnt vmcnt(" #n ")" ::: "memory")
#define WAIT_LGKM0() asm volatile("s_waitcnt lgkmcnt(0)" ::: "memory")
#define BAR() __builtin_amdgcn_s_barrier()

__global__ __launch_bounds__(256)
void gather_cast_k(const int* __restrict__ X, const float* __restrict__ emb,
                   unsigned short* __restrict__ e) {
    int s = blockIdx.x;
    long long row = X[s];
    const float* src = emb + row * 2048 + threadIdx.x * 8;
    float4 f0 = *(const float4*)(src);
    float4 f1 = *(const float4*)(src + 4);
    ushort8_t v;
    v[0] = f2bf(f0.x); v[1] = f2bf(f0.y); v[2] = f2bf(f0.z); v[3] = f2bf(f0.w);
    v[4] = f2bf(f1.x); v[5] = f2bf(f1.y); v[6] = f2bf(f1.z); v[7] = f2bf(f1.w);
    *(ushort8_t*)(e + (size_t)s * 2048 + threadIdx.x * 8) = v;
}

// f32 -> bf16 weight convert, 4 segments (counts in 2048-elem blocks)
__global__ __launch_bounds__(256)
void wconv4_k(const float* __restrict__ s0, unsigned short* __restrict__ d0, int c0,
              const float* __restrict__ s1, unsigned short* __restrict__ d1, int c1,
              const float* __restrict__ s2, unsigned short* __restrict__ d2, int c2,
              const float* __restrict__ s3, unsigned short* __restrict__ d3) {
    int b = blockIdx.x;
    const float* s; unsigned short* d; int off;
    if (b < c0) { s = s0; d = d0; off = b; }
    else if (b < c0 + c1) { s = s1; d = d1; off = b - c0; }
    else if (b < c0 + c1 + c2) { s = s2; d = d2; off = b - c0 - c1; }
    else { s = s3; d = d3; off = b - c0 - c1 - c2; }
    size_t idx = ((size_t)off * 256 + threadIdx.x) * 8;
    float4 f0 = *(const float4*)(s + idx);
    float4 f1 = *(const float4*)(s + idx + 4);
    ushort8_t v;
    v[0] = f2bf(f0.x); v[1] = f2bf(f0.y); v[2] = f2bf(f0.z); v[3] = f2bf(f0.w);
    v[4] = f2bf(f1.x); v[5] = f2bf(f1.y); v[6] = f2bf(f1.z); v[7] = f2bf(f1.w);
    *(ushort8_t*)(d + idx) = v;
}

// C[m][n] = sum_k A[m][k] * W[n][k], A,W bf16 [*][2048]. 128x128 tile, BK=64,
// double-buffered global_load_lds, counted vmcnt, raw barriers. REP: diagnostic repeat.
template<int REP>
__global__ __launch_bounds__(256)
void gemm_p2_k(const unsigned short* __restrict__ A,
               const unsigned short* __restrict__ W0, const unsigned short* __restrict__ W1,
               const unsigned short* __restrict__ W2,
               void* __restrict__ C0, void* __restrict__ C1, void* __restrict__ C2,
               int t1, int t2, int ldc0, int ldc1, int ldc2,
               int om0, int om1, int om2, const float* __restrict__ bias) {
    __shared__ unsigned short As[2 * 128 * 64];
    __shared__ unsigned short Bs[2 * 128 * 64];
    const int cpx = gridDim.x >> 3;
    int id = blockIdx.x;
    int swz = (id & 7) * cpx + (id >> 3);
    const int bx = swz & 15;
    const int by = swz >> 4;
    const unsigned short* Wp; void* Cp; int ldc, om, nb;
    if (by < t1)      { Wp = W0; Cp = C0; ldc = ldc0; om = om0; nb = by; }
    else if (by < t2) { Wp = W1; Cp = C1; ldc = ldc1; om = om1; nb = by - t1; }
    else              { Wp = W2; Cp = C2; ldc = ldc2; om = om2; nb = by - t2; }
    const int m0 = bx * 128, n0 = nb * 128;
    const int tid = threadIdx.x, lane = tid & 63, w = tid >> 6;
    const int wm = (w >> 1) * 64, wn = (w & 1) * 64;
    const int lr = lane & 15, lg = lane >> 4;
    const int srow = tid >> 3, sj = tid & 7;

    #define G_STAGE(buf, k0)                                                          \
        _Pragma("unroll")                                                             \
        for (int i = 0; i < 4; i++) {                                                 \
            int row = srow + i * 32;                                                  \
            unsigned short* ad = As + (buf) * 8192 + (w * 64 + i * 256) * 8;          \
            unsigned short* bd = Bs + (buf) * 8192 + (w * 64 + i * 256) * 8;          \
            gload16(A  + (size_t)(m0 + row) * 2048 + (k0) + sj * 8, ad);              \
            gload16(Wp + (size_t)(n0 + row) * 2048 + (k0) + sj * 8, bd);              \
        }

    for (int rep = 0; rep < REP; ++rep) {
        f32x4 acc[4][4];
        #pragma unroll
        for (int i = 0; i < 4; i++)
            #pragma unroll
            for (int j = 0; j < 4; j++) acc[i][j] = {};

        G_STAGE(0, 0);
        for (int s = 0; s < 32; ++s) {
            const int cur = s & 1;
            if (s < 31) {
                G_STAGE(cur ^ 1, (s + 1) * 64);
                WAIT_VM(8);
            } else {
                WAIT_VM(0);
            }
            BAR();
            const unsigned short* Asb = As + cur * 8192;
            const unsigned short* Bsb = Bs + cur * 8192;
            #pragma unroll
            for (int kk = 0; kk < 2; kk++) {
                bf16x8 af[4], bfr[4];
                #pragma unroll
                for (int mi = 0; mi < 4; mi++)
                    af[mi] = *(const bf16x8*)(&Asb[(wm + mi * 16 + lr) * 64 + kk * 32 + lg * 8]);
                #pragma unroll
                for (int ni = 0; ni < 4; ni++)
                    bfr[ni] = *(const bf16x8*)(&Bsb[(wn + ni * 16 + lr) * 64 + kk * 32 + lg * 8]);
                #pragma unroll
                for (int mi = 0; mi < 4; mi++)
                    #pragma unroll
                    for (int ni = 0; ni < 4; ni++)
                        acc[mi][ni] = mfma16(af[mi], bfr[ni], acc[mi][ni]);
            }
            WAIT_LGKM0();
            BAR();
        }

        #pragma unroll
        for (int mi = 0; mi < 4; mi++)
            #pragma unroll
            for (int ni = 0; ni < 4; ni++) {
                int col = n0 + wn + ni * 16 + lr;
                #pragma unroll
                for (int jj = 0; jj < 4; jj++) {
                    int rowg = m0 + wm + mi * 16 + lg * 4 + jj;
                    float vv = acc[mi][ni][jj];
                    if (om == 0) {
                        ((unsigned short*)Cp)[(size_t)rowg * ldc + col] = f2bf(vv);
                    } else if (om == 1) {
                        ((float*)Cp)[(size_t)rowg * ldc + col] = vv + bias[col];
                    } else {
                        ((unsigned short*)Cp)[(size_t)col * ldc + rowg] = f2bf(vv);
                    }
                }
            }
    }
    #undef G_STAGE
}

// Flash attention. Grid 512 (XCD-chunked: ikv == blockIdx%8). 4 waves x 32 q-rows.
// Double-buffered global_load_lds with pre-swizzled source. setprio around MFMA.
template<int REP>
__global__ __launch_bounds__(256)
void attn2_k(const unsigned short* __restrict__ Qb, const unsigned short* __restrict__ Kb,
             const unsigned short* __restrict__ VbT, unsigned short* __restrict__ Ctx) {
    __shared__ unsigned short Ks[2 * 64 * 64];
    __shared__ unsigned short Vts[2 * 64 * 64];
    int id = blockIdx.x;
    int swz = (id & 7) * 64 + (id >> 3);   // XCD c owns heads 4c..4c+3 (KV L2-resident)
    const int hq = swz >> 4;
    const int qt = swz & 15;
    const int ikv = hq >> 2;
    const int tid = threadIdx.x, lane = tid & 63, w = tid >> 6;
    const int l31 = lane & 31, hi = lane >> 5;
    const int qrow = qt * 128 + w * 32 + l31;
    const float CS = 0.125f * 1.44269504088896f;  // 1/sqrt(64) * log2(e)
    const int srow = tid >> 3, sj = tid & 7;

    #define A_STAGE(buf, t0)                                                          \
        _Pragma("unroll")                                                             \
        for (int i = 0; i < 2; i++) {                                                 \
            int row = srow + i * 32;                                                  \
            int jj = sj ^ (row & 7);                                                  \
            unsigned short* kd = Ks + (buf) * 4096 + (w * 64 + i * 256) * 8;          \
            unsigned short* vd = Vts + (buf) * 4096 + (w * 64 + i * 256) * 8;         \
            gload16(Kb + (size_t)((t0) + row) * 512 + ikv * 64 + jj * 8, kd);         \
            gload16(VbT + (size_t)(ikv * 64 + row) * 2048 + (t0) + jj * 8, vd);       \
        }

    for (int rep = 0; rep < REP; ++rep) {
        bf16x8 qf[4];
        #pragma unroll
        for (int ks = 0; ks < 4; ks++)
            qf[ks] = *(const bf16x8*)(Qb + (size_t)qrow * 2048 + hq * 64 + ks * 16 + hi * 8);

        f32x16 oacc0 = {}, oacc1 = {};
        float m = -1e30f, l = 0.0f;

        A_STAGE(0, 0);
        for (int t = 0; t < 32; ++t) {
            const int cur = t & 1;
            if (t < 31) {
                A_STAGE(cur ^ 1, (t + 1) * 64);
                WAIT_VM(4);
            } else {
                WAIT_VM(0);
            }
            BAR();
            const unsigned short* Ksb = Ks + cur * 4096;
            const unsigned short* Vsb = Vts + cur * 4096;

            // S^T = K Q^T
            f32x16 s0 = {}, s1 = {};
            __builtin_amdgcn_s_setprio(1);
            #pragma unroll
            for (int ks = 0; ks < 4; ks++) {
                int gr = (2 * ks + hi) ^ (l31 & 7);
                bf16x8 kf0 = *(const bf16x8*)(&Ksb[l31 * 64 + gr * 8]);
                bf16x8 kf1 = *(const bf16x8*)(&Ksb[(32 + l31) * 64 + gr * 8]);
                s0 = mfma32(kf0, qf[ks], s0);
                s1 = mfma32(kf1, qf[ks], s1);
            }
            __builtin_amdgcn_s_setprio(0);

            // online softmax: lane owns q-row l31; tree reductions
            float mx[8];
            #pragma unroll
            for (int r = 0; r < 8; r++)
                mx[r] = fmaxf(fmaxf(s0[2 * r], s0[2 * r + 1]),
                              fmaxf(s1[2 * r], s1[2 * r + 1]));
            #pragma unroll
            for (int st = 4; st > 0; st >>= 1)
                #pragma unroll
                for (int r = 0; r < st; r++) mx[r] = fmaxf(mx[r], mx[r + st]);
            float pmax = fmaxf(mx[0], __shfl_xor(mx[0], 32, 64));
            pmax *= CS;

            if (!__all(pmax <= m + 8.0f)) {
                float mnew = fmaxf(m, pmax);
                float sc = exp2f(m - mnew);
                m = mnew;
                l *= sc;
                #pragma unroll
                for (int r = 0; r < 16; r++) {
                    const int qp = (r & 3) + 8 * (r >> 2);
                    float scv = __shfl(sc, qp + 4 * hi, 64);
                    oacc0[r] *= scv;
                    oacc1[r] *= scv;
                }
            }

            float rs0 = 0.f, rs1 = 0.f, rs2 = 0.f, rs3 = 0.f;
            #pragma unroll
            for (int r = 0; r < 16; r += 4) {
                float p0 = exp2f(__builtin_fmaf(s0[r],     CS, -m)); s0[r]     = p0; rs0 += p0;
                float p1 = exp2f(__builtin_fmaf(s0[r + 1], CS, -m)); s0[r + 1] = p1; rs1 += p1;
                float p2 = exp2f(__builtin_fmaf(s0[r + 2], CS, -m)); s0[r + 2] = p2; rs2 += p2;
                float p3 = exp2f(__builtin_fmaf(s0[r + 3], CS, -m)); s0[r + 3] = p3; rs3 += p3;
            }
            #pragma unroll
            for (int r = 0; r < 16; r += 4) {
                float p0 = exp2f(__builtin_fmaf(s1[r],     CS, -m)); s1[r]     = p0; rs0 += p0;
                float p1 = exp2f(__builtin_fmaf(s1[r + 1], CS, -m)); s1[r + 1] = p1; rs1 += p1;
                float p2 = exp2f(__builtin_fmaf(s1[r + 2], CS, -m)); s1[r + 2] = p2; rs2 += p2;
                float p3 = exp2f(__builtin_fmaf(s1[r + 3], CS, -m)); s1[r + 3] = p3; rs3 += p3;
            }
            float rs = (rs0 + rs1) + (rs2 + rs3);
            rs += __shfl_xor(rs, 32, 64);
            l += rs;

            // pack P -> A-fragments (cvt_pk + permlane32_swap)
            uint4_t pw[4];
            #pragma unroll
            for (int c = 0; c < 2; c++) {
                unsigned a   = cvtpk(s0[8 * c + 0], s0[8 * c + 1]);
                unsigned bb  = cvtpk(s0[8 * c + 2], s0[8 * c + 3]);
                unsigned cc2 = cvtpk(s0[8 * c + 4], s0[8 * c + 5]);
                unsigned dd  = cvtpk(s0[8 * c + 6], s0[8 * c + 7]);
                plswap(a, cc2); plswap(bb, dd);
                pw[c][0] = a; pw[c][1] = bb; pw[c][2] = cc2; pw[c][3] = dd;
            }
            #pragma unroll
            for (int c = 0; c < 2; c++) {
                unsigned a   = cvtpk(s1[8 * c + 0], s1[8 * c + 1]);
                unsigned bb  = cvtpk(s1[8 * c + 2], s1[8 * c + 3]);
                unsigned cc2 = cvtpk(s1[8 * c + 4], s1[8 * c + 5]);
                unsigned dd  = cvtpk(s1[8 * c + 6], s1[8 * c + 7]);
                plswap(a, cc2); plswap(bb, dd);
                pw[2 + c][0] = a; pw[2 + c][1] = bb; pw[2 + c][2] = cc2; pw[2 + c][3] = dd;
            }

            // PV
            __builtin_amdgcn_s_setprio(1);
            #pragma unroll
            for (int ks = 0; ks < 4; ks++) {
                bf16x8 pa = __builtin_bit_cast(bf16x8, pw[ks]);
                int gr = (2 * ks + hi) ^ (l31 & 7);
                bf16x8 vf0 = *(const bf16x8*)(&Vsb[l31 * 64 + gr * 8]);
                bf16x8 vf1 = *(const bf16x8*)(&Vsb[(32 + l31) * 64 + gr * 8]);
                oacc0 = mfma32(pa, vf0, oacc0);
                oacc1 = mfma32(pa, vf1, oacc1);
            }
            __builtin_amdgcn_s_setprio(0);
            WAIT_LGKM0();
            BAR();
        }

        float linv = 1.0f / l;
        #pragma unroll
        for (int r = 0; r < 16; r++) {
            const int qp = (r & 3) + 8 * (r >> 2);
            float lv = __shfl(linv, qp + 4 * hi, 64);
            int row = qt * 128 + w * 32 + qp + 4 * hi;
            Ctx[(size_t)row * 2048 + hq * 64 + l31]      = f2bf(oacc0[r] * lv);
            Ctx[(size_t)row * 2048 + hq * 64 + 32 + l31] = f2bf(oacc1[r] * lv);
        }
    }
    #undef A_STAGE
}

extern "C" void kernel_launch(void* const* d_in, const int* in_sizes, int n_in,
                              void* d_out, int out_size, void* d_ws, size_t ws_size,
                              hipStream_t stream) {
    (void)in_sizes; (void)n_in; (void)out_size; (void)ws_size;
    const int*   X   = (const int*)d_in[0];
    const float* emb = (const float*)d_in[1];
    const float* Wk  = (const float*)d_in[2];
    const float* Wv  = (const float*)d_in[3];
    const float* Wq  = (const float*)d_in[4];
    const float* Wo  = (const float*)d_in[5];
    const float* Wb  = (const float*)d_in[6];

    unsigned short* e   = (unsigned short*)d_ws;
    unsigned short* Kb  = e   + (size_t)2048 * 2048;
    unsigned short* VbT = Kb  + (size_t)2048 * 512;
    unsigned short* Qb  = VbT + (size_t)512 * 2048;
    unsigned short* Ctx = Qb  + (size_t)2048 * 2048;
    unsigned short* Wkb = Ctx + (size_t)2048 * 2048;
    unsigned short* Wvb = Wkb + (size_t)512 * 2048;
    unsigned short* Wqb = Wvb + (size_t)512 * 2048;
    unsigned short* Wob = Wqb + (size_t)2048 * 2048;

    gather_cast_k<<<dim3(2048), dim3(256), 0, stream>>>(X, emb, e);
    wconv4_k<<<dim3(5120), dim3(256), 0, stream>>>(Wk, Wkb, 512, Wv, Wvb, 512,
                                                   Wq, Wqb, 2048, Wo, Wob);
    // fused QKV: by<16 Wq->Qb; by<20 Wk->Kb; else Wv->VbT (transposed). REP=6 diagnostic.
    gemm_p2_k<6><<<dim3(384), dim3(256), 0, stream>>>(e, Wqb, Wkb, Wvb,
                                                      (void*)Qb, (void*)Kb, (void*)VbT,
                                                      16, 20, 2048, 512, 2048,
                                                      0, 0, 2, nullptr);
    attn2_k<4><<<dim3(512), dim3(256), 0, stream>>>(Qb, Kb, VbT, Ctx);
    gemm_p2_k<8><<<dim3(256), dim3(256), 0, stream>>>(Ctx, Wob, Wob, Wob,
                                                      d_out, d_out, d_out,
                                                      16, 32, 2048, 2048, 2048,
                                                      1, 1, 1, Wb);
}

// Round 6
// 166.230 us; speedup vs baseline: 7.9653x; 7.9653x over previous
//
#include <hip/hip_runtime.h>

// GQA forward: prep(gather+wconv) -> fused QKV proj -> flash attn -> out proj.
// GEMMs: 128x128 2-phase dbuf global_load_lds(16B), counted vmcnt, raw barriers,
// XOR-swizzled LDS (source pre-swizzle granule sj^(row&7), read (kk*4+lg)^(lr&7)).
// Attention: swapped-QK^T 32x32x16, in-register softmax, XOR-swizzled K/V^T,
// XCD-chunked head mapping, setprio around MFMA.
// ws (ushort elems): e[4M] Kb[1M] VbT[1M] Qb[4M] Ctx[4M] Wkb[1M] Wvb[1M] Wqb[4M] Wob[4M].

typedef __bf16 bf16x8 __attribute__((ext_vector_type(8)));
typedef float f32x4 __attribute__((ext_vector_type(4)));
typedef float f32x16 __attribute__((ext_vector_type(16)));
typedef unsigned short ushort8_t __attribute__((ext_vector_type(8)));
typedef unsigned int uint4_t __attribute__((ext_vector_type(4)));

#define DEVI static __device__ __forceinline__

DEVI unsigned short f2bf(float f) {
    union { float f; unsigned int u; } c; c.f = f;
    unsigned int u = c.u;
    unsigned int r = (u + 0x7FFFu + ((u >> 16) & 1u)) >> 16;  // RNE
    return (unsigned short)r;
}

DEVI f32x4 mfma16(bf16x8 a, bf16x8 b, f32x4 c) {
    return __builtin_amdgcn_mfma_f32_16x16x32_bf16(a, b, c, 0, 0, 0);
}
DEVI f32x16 mfma32(bf16x8 a, bf16x8 b, f32x16 c) {
    return __builtin_amdgcn_mfma_f32_32x32x16_bf16(a, b, c, 0, 0, 0);
}
DEVI unsigned cvtpk(float a, float b) {
    unsigned r;
    asm("v_cvt_pk_bf16_f32 %0, %1, %2" : "=v"(r) : "v"(a), "v"(b));
    return r;
}
DEVI void plswap(unsigned& a, unsigned& b) {
    asm("v_permlane32_swap_b32 %0, %1" : "+v"(a), "+v"(b));
}
DEVI void gload16(const unsigned short* g, unsigned short* l) {
    __builtin_amdgcn_global_load_lds(
        (const __attribute__((address_space(1))) void*)g,
        (__attribute__((address_space(3))) void*)l, 16, 0, 0);
}
#define WAIT_VM(n) asm volatile("s_waitcnt vmcnt(" #n ")" ::: "memory")
#define WAIT_LGKM0() asm volatile("s_waitcnt lgkmcnt(0)" ::: "memory")
#define BAR() __builtin_amdgcn_s_barrier()

DEVI void cvt8(const float* src, unsigned short* dst) {
    float4 f0 = *(const float4*)(src);
    float4 f1 = *(const float4*)(src + 4);
    ushort8_t v;
    v[0] = f2bf(f0.x); v[1] = f2bf(f0.y); v[2] = f2bf(f0.z); v[3] = f2bf(f0.w);
    v[4] = f2bf(f1.x); v[5] = f2bf(f1.y); v[6] = f2bf(f1.z); v[7] = f2bf(f1.w);
    *(ushort8_t*)(dst) = v;
}

// blocks 0..2047: gather+cast e; 2048+: weight converts (counts in 2048-elem rows)
__global__ __launch_bounds__(256)
void prep_k(const int* __restrict__ X, const float* __restrict__ emb,
            unsigned short* __restrict__ e,
            const float* __restrict__ Wk, unsigned short* __restrict__ Wkb,
            const float* __restrict__ Wv, unsigned short* __restrict__ Wvb,
            const float* __restrict__ Wq, unsigned short* __restrict__ Wqb,
            const float* __restrict__ Wo, unsigned short* __restrict__ Wob) {
    int b = blockIdx.x;
    if (b < 2048) {
        long long row = X[b];
        cvt8(emb + row * 2048 + threadIdx.x * 8, e + (size_t)b * 2048 + threadIdx.x * 8);
        return;
    }
    b -= 2048;
    const float* s; unsigned short* d; int off;
    if (b < 512) { s = Wk; d = Wkb; off = b; }
    else if (b < 1024) { s = Wv; d = Wvb; off = b - 512; }
    else if (b < 3072) { s = Wq; d = Wqb; off = b - 1024; }
    else { s = Wo; d = Wob; off = b - 3072; }
    size_t idx = ((size_t)off * 256 + threadIdx.x) * 8;
    cvt8(s + idx, d + idx);
}

// C[m][n] = sum_k A[m][k] * W[n][k], A,W bf16 [*][2048]. 128x128 tile, BK=64,
// 2-phase dbuf global_load_lds, counted vmcnt, XOR-swizzled LDS granules.
// by<T1 -> seg0, by<T2 -> seg1, else seg2. OM: 0 bf16; 1 f32+bias; 2 bf16 transposed.
template<int OM0, int OM1, int OM2>
__global__ __launch_bounds__(256)
void gemm_swz_k(const unsigned short* __restrict__ A,
                const unsigned short* __restrict__ W0, const unsigned short* __restrict__ W1,
                const unsigned short* __restrict__ W2,
                void* __restrict__ C0, void* __restrict__ C1, void* __restrict__ C2,
                int t1, int t2, int ldc0, int ldc1, int ldc2,
                const float* __restrict__ bias) {
    __shared__ unsigned short As[2 * 128 * 64];
    __shared__ unsigned short Bs[2 * 128 * 64];
    const int cpx = gridDim.x >> 3;
    int id = blockIdx.x;
    int swz = (id & 7) * cpx + (id >> 3);
    const int bx = swz & 15;
    const int by = swz >> 4;
    const unsigned short* Wp; void* Cp; int ldc, om, nb;
    if (by < t1)      { Wp = W0; Cp = C0; ldc = ldc0; om = OM0; nb = by; }
    else if (by < t2) { Wp = W1; Cp = C1; ldc = ldc1; om = OM1; nb = by - t1; }
    else              { Wp = W2; Cp = C2; ldc = ldc2; om = OM2; nb = by - t2; }
    const int m0 = bx * 128, n0 = nb * 128;
    const int tid = threadIdx.x, lane = tid & 63, w = tid >> 6;
    const int wm = (w >> 1) * 64, wn = (w & 1) * 64;
    const int lr = lane & 15, lg = lane >> 4;
    const int srow = tid >> 3, sj = tid & 7;

    f32x4 acc[4][4];
    #pragma unroll
    for (int i = 0; i < 4; i++)
        #pragma unroll
        for (int j = 0; j < 4; j++) acc[i][j] = {};

    // stage: LDS dest is lane-linear; global source granule pre-swizzled sj^(row&7)
    #define G_STAGE(buf, k0)                                                          \
        _Pragma("unroll")                                                             \
        for (int i = 0; i < 4; i++) {                                                 \
            int row = srow + i * 32;                                                  \
            int jj = sj ^ (row & 7);                                                  \
            unsigned short* ad = As + (buf) * 8192 + (w * 64 + i * 256) * 8;          \
            unsigned short* bd = Bs + (buf) * 8192 + (w * 64 + i * 256) * 8;          \
            gload16(A  + (size_t)(m0 + row) * 2048 + (k0) + jj * 8, ad);              \
            gload16(Wp + (size_t)(n0 + row) * 2048 + (k0) + jj * 8, bd);              \
        }

    G_STAGE(0, 0);
    for (int s = 0; s < 32; ++s) {
        const int cur = s & 1;
        if (s < 31) {
            G_STAGE(cur ^ 1, (s + 1) * 64);
            WAIT_VM(8);
        } else {
            WAIT_VM(0);
        }
        BAR();
        const unsigned short* Asb = As + cur * 8192;
        const unsigned short* Bsb = Bs + cur * 8192;
        #pragma unroll
        for (int kk = 0; kk < 2; kk++) {
            bf16x8 af[4], bfr[4];
            #pragma unroll
            for (int mi = 0; mi < 4; mi++) {
                int r = wm + mi * 16 + lr;
                int g = (kk * 4 + lg) ^ (r & 7);
                af[mi] = *(const bf16x8*)(&Asb[r * 64 + g * 8]);
            }
            #pragma unroll
            for (int ni = 0; ni < 4; ni++) {
                int r = wn + ni * 16 + lr;
                int g = (kk * 4 + lg) ^ (r & 7);
                bfr[ni] = *(const bf16x8*)(&Bsb[r * 64 + g * 8]);
            }
            __builtin_amdgcn_s_setprio(1);
            #pragma unroll
            for (int mi = 0; mi < 4; mi++)
                #pragma unroll
                for (int ni = 0; ni < 4; ni++)
                    acc[mi][ni] = mfma16(af[mi], bfr[ni], acc[mi][ni]);
            __builtin_amdgcn_s_setprio(0);
        }
        WAIT_LGKM0();
        BAR();
    }
    #undef G_STAGE

    #pragma unroll
    for (int mi = 0; mi < 4; mi++)
        #pragma unroll
        for (int ni = 0; ni < 4; ni++) {
            int col = n0 + wn + ni * 16 + lr;
            #pragma unroll
            for (int jj = 0; jj < 4; jj++) {
                int rowg = m0 + wm + mi * 16 + lg * 4 + jj;
                float vv = acc[mi][ni][jj];
                if (om == 0) {
                    ((unsigned short*)Cp)[(size_t)rowg * ldc + col] = f2bf(vv);
                } else if (om == 1) {
                    ((float*)Cp)[(size_t)rowg * ldc + col] = vv + bias[col];
                } else {
                    ((unsigned short*)Cp)[(size_t)col * ldc + rowg] = f2bf(vv);
                }
            }
        }
}

// Flash attention. Grid 512 (XCD-chunked: ikv == blockIdx%8). 4 waves x 32 q-rows.
// Double-buffered global_load_lds with pre-swizzled source. setprio around MFMA.
__global__ __launch_bounds__(256)
void attn2_k(const unsigned short* __restrict__ Qb, const unsigned short* __restrict__ Kb,
             const unsigned short* __restrict__ VbT, unsigned short* __restrict__ Ctx) {
    __shared__ unsigned short Ks[2 * 64 * 64];
    __shared__ unsigned short Vts[2 * 64 * 64];
    int id = blockIdx.x;
    int swz = (id & 7) * 64 + (id >> 3);   // XCD c owns heads 4c..4c+3 (KV L2-resident)
    const int hq = swz >> 4;
    const int qt = swz & 15;
    const int ikv = hq >> 2;
    const int tid = threadIdx.x, lane = tid & 63, w = tid >> 6;
    const int l31 = lane & 31, hi = lane >> 5;
    const int qrow = qt * 128 + w * 32 + l31;
    const float CS = 0.125f * 1.44269504088896f;  // 1/sqrt(64) * log2(e)
    const int srow = tid >> 3, sj = tid & 7;

    bf16x8 qf[4];
    #pragma unroll
    for (int ks = 0; ks < 4; ks++)
        qf[ks] = *(const bf16x8*)(Qb + (size_t)qrow * 2048 + hq * 64 + ks * 16 + hi * 8);

    f32x16 oacc0 = {}, oacc1 = {};
    float m = -1e30f, l = 0.0f;

    #define A_STAGE(buf, t0)                                                          \
        _Pragma("unroll")                                                             \
        for (int i = 0; i < 2; i++) {                                                 \
            int row = srow + i * 32;                                                  \
            int jj = sj ^ (row & 7);                                                  \
            unsigned short* kd = Ks + (buf) * 4096 + (w * 64 + i * 256) * 8;          \
            unsigned short* vd = Vts + (buf) * 4096 + (w * 64 + i * 256) * 8;         \
            gload16(Kb + (size_t)((t0) + row) * 512 + ikv * 64 + jj * 8, kd);         \
            gload16(VbT + (size_t)(ikv * 64 + row) * 2048 + (t0) + jj * 8, vd);       \
        }

    A_STAGE(0, 0);
    for (int t = 0; t < 32; ++t) {
        const int cur = t & 1;
        if (t < 31) {
            A_STAGE(cur ^ 1, (t + 1) * 64);
            WAIT_VM(4);
        } else {
            WAIT_VM(0);
        }
        BAR();
        const unsigned short* Ksb = Ks + cur * 4096;
        const unsigned short* Vsb = Vts + cur * 4096;

        // S^T = K Q^T
        f32x16 s0 = {}, s1 = {};
        __builtin_amdgcn_s_setprio(1);
        #pragma unroll
        for (int ks = 0; ks < 4; ks++) {
            int gr = (2 * ks + hi) ^ (l31 & 7);
            bf16x8 kf0 = *(const bf16x8*)(&Ksb[l31 * 64 + gr * 8]);
            bf16x8 kf1 = *(const bf16x8*)(&Ksb[(32 + l31) * 64 + gr * 8]);
            s0 = mfma32(kf0, qf[ks], s0);
            s1 = mfma32(kf1, qf[ks], s1);
        }
        __builtin_amdgcn_s_setprio(0);

        // online softmax: lane owns q-row l31; tree reductions
        float mx[8];
        #pragma unroll
        for (int r = 0; r < 8; r++)
            mx[r] = fmaxf(fmaxf(s0[2 * r], s0[2 * r + 1]),
                          fmaxf(s1[2 * r], s1[2 * r + 1]));
        #pragma unroll
        for (int st = 4; st > 0; st >>= 1)
            #pragma unroll
            for (int r = 0; r < st; r++) mx[r] = fmaxf(mx[r], mx[r + st]);
        float pmax = fmaxf(mx[0], __shfl_xor(mx[0], 32, 64));
        pmax *= CS;

        if (!__all(pmax <= m + 8.0f)) {
            float mnew = fmaxf(m, pmax);
            float sc = exp2f(m - mnew);
            m = mnew;
            l *= sc;
            #pragma unroll
            for (int r = 0; r < 16; r++) {
                const int qp = (r & 3) + 8 * (r >> 2);
                float scv = __shfl(sc, qp + 4 * hi, 64);
                oacc0[r] *= scv;
                oacc1[r] *= scv;
            }
        }

        float rs0 = 0.f, rs1 = 0.f, rs2 = 0.f, rs3 = 0.f;
        #pragma unroll
        for (int r = 0; r < 16; r += 4) {
            float p0 = exp2f(__builtin_fmaf(s0[r],     CS, -m)); s0[r]     = p0; rs0 += p0;
            float p1 = exp2f(__builtin_fmaf(s0[r + 1], CS, -m)); s0[r + 1] = p1; rs1 += p1;
            float p2 = exp2f(__builtin_fmaf(s0[r + 2], CS, -m)); s0[r + 2] = p2; rs2 += p2;
            float p3 = exp2f(__builtin_fmaf(s0[r + 3], CS, -m)); s0[r + 3] = p3; rs3 += p3;
        }
        #pragma unroll
        for (int r = 0; r < 16; r += 4) {
            float p0 = exp2f(__builtin_fmaf(s1[r],     CS, -m)); s1[r]     = p0; rs0 += p0;
            float p1 = exp2f(__builtin_fmaf(s1[r + 1], CS, -m)); s1[r + 1] = p1; rs1 += p1;
            float p2 = exp2f(__builtin_fmaf(s1[r + 2], CS, -m)); s1[r + 2] = p2; rs2 += p2;
            float p3 = exp2f(__builtin_fmaf(s1[r + 3], CS, -m)); s1[r + 3] = p3; rs3 += p3;
        }
        float rs = (rs0 + rs1) + (rs2 + rs3);
        rs += __shfl_xor(rs, 32, 64);
        l += rs;

        // pack P -> A-fragments (cvt_pk + permlane32_swap)
        uint4_t pw[4];
        #pragma unroll
        for (int c = 0; c < 2; c++) {
            unsigned a   = cvtpk(s0[8 * c + 0], s0[8 * c + 1]);
            unsigned bb  = cvtpk(s0[8 * c + 2], s0[8 * c + 3]);
            unsigned cc2 = cvtpk(s0[8 * c + 4], s0[8 * c + 5]);
            unsigned dd  = cvtpk(s0[8 * c + 6], s0[8 * c + 7]);
            plswap(a, cc2); plswap(bb, dd);
            pw[c][0] = a; pw[c][1] = bb; pw[c][2] = cc2; pw[c][3] = dd;
        }
        #pragma unroll
        for (int c = 0; c < 2; c++) {
            unsigned a   = cvtpk(s1[8 * c + 0], s1[8 * c + 1]);
            unsigned bb  = cvtpk(s1[8 * c + 2], s1[8 * c + 3]);
            unsigned cc2 = cvtpk(s1[8 * c + 4], s1[8 * c + 5]);
            unsigned dd  = cvtpk(s1[8 * c + 6], s1[8 * c + 7]);
            plswap(a, cc2); plswap(bb, dd);
            pw[2 + c][0] = a; pw[2 + c][1] = bb; pw[2 + c][2] = cc2; pw[2 + c][3] = dd;
        }

        // PV
        __builtin_amdgcn_s_setprio(1);
        #pragma unroll
        for (int ks = 0; ks < 4; ks++) {
            bf16x8 pa = __builtin_bit_cast(bf16x8, pw[ks]);
            int gr = (2 * ks + hi) ^ (l31 & 7);
            bf16x8 vf0 = *(const bf16x8*)(&Vsb[l31 * 64 + gr * 8]);
            bf16x8 vf1 = *(const bf16x8*)(&Vsb[(32 + l31) * 64 + gr * 8]);
            oacc0 = mfma32(pa, vf0, oacc0);
            oacc1 = mfma32(pa, vf1, oacc1);
        }
        __builtin_amdgcn_s_setprio(0);
        WAIT_LGKM0();
        BAR();
    }
    #undef A_STAGE

    float linv = 1.0f / l;
    #pragma unroll
    for (int r = 0; r < 16; r++) {
        const int qp = (r & 3) + 8 * (r >> 2);
        float lv = __shfl(linv, qp + 4 * hi, 64);
        int row = qt * 128 + w * 32 + qp + 4 * hi;
        Ctx[(size_t)row * 2048 + hq * 64 + l31]      = f2bf(oacc0[r] * lv);
        Ctx[(size_t)row * 2048 + hq * 64 + 32 + l31] = f2bf(oacc1[r] * lv);
    }
}

extern "C" void kernel_launch(void* const* d_in, const int* in_sizes, int n_in,
                              void* d_out, int out_size, void* d_ws, size_t ws_size,
                              hipStream_t stream) {
    (void)in_sizes; (void)n_in; (void)out_size; (void)ws_size;
    const int*   X   = (const int*)d_in[0];
    const float* emb = (const float*)d_in[1];
    const float* Wk  = (const float*)d_in[2];
    const float* Wv  = (const float*)d_in[3];
    const float* Wq  = (const float*)d_in[4];
    const float* Wo  = (const float*)d_in[5];
    const float* Wb  = (const float*)d_in[6];

    unsigned short* e   = (unsigned short*)d_ws;
    unsigned short* Kb  = e   + (size_t)2048 * 2048;
    unsigned short* VbT = Kb  + (size_t)2048 * 512;
    unsigned short* Qb  = VbT + (size_t)512 * 2048;
    unsigned short* Ctx = Qb  + (size_t)2048 * 2048;
    unsigned short* Wkb = Ctx + (size_t)2048 * 2048;
    unsigned short* Wvb = Wkb + (size_t)512 * 2048;
    unsigned short* Wqb = Wvb + (size_t)512 * 2048;
    unsigned short* Wob = Wqb + (size_t)2048 * 2048;

    prep_k<<<dim3(2048 + 5120), dim3(256), 0, stream>>>(X, emb, e, Wk, Wkb, Wv, Wvb,
                                                        Wq, Wqb, Wo, Wob);
    // fused QKV: by<16 Wq->Qb; by<20 Wk->Kb; else Wv->VbT (transposed)
    gemm_swz_k<0, 0, 2><<<dim3(384), dim3(256), 0, stream>>>(
        e, Wqb, Wkb, Wvb, (void*)Qb, (void*)Kb, (void*)VbT,
        16, 20, 2048, 512, 2048, nullptr);
    attn2_k<<<dim3(512), dim3(256), 0, stream>>>(Qb, Kb, VbT, Ctx);
    gemm_swz_k<1, 1, 1><<<dim3(256), dim3(256), 0, stream>>>(
        Ctx, Wob, Wob, Wob, d_out, d_out, d_out,
        16, 32, 2048, 2048, 2048, Wb);
}

// Round 7
// 162.850 us; speedup vs baseline: 8.1307x; 1.0208x over previous
//
#include <hip/hip_runtime.h>

// GQA forward: prep(gather+wconv) -> fused QKV proj -> flash attn -> out proj.
// GEMMs: 128x128 2-phase dbuf global_load_lds(16B), counted vmcnt, raw barriers,
// XOR-swizzled LDS (source pre-swizzle granule sj^(row&7), read (kk*4+lg)^(lr&7)).
// Attention R7: swapped-QK^T 32x32x16, Q pre-scaled by 0.125*log2e (OM=3 epilogue),
// max3 reduction tree, row-sum l accumulated via MFMA ones-trick (reg-layout, no
// shuffles), in-register P pack (cvt_pk + permlane32_swap), XOR-swizzled K/V^T,
// XCD-chunked head mapping, setprio around MFMA.
// ws (ushort elems): e[4M] Kb[1M] VbT[1M] Qb[4M] Ctx[4M] Wkb[1M] Wvb[1M] Wqb[4M] Wob[4M].

typedef __bf16 bf16x8 __attribute__((ext_vector_type(8)));
typedef float f32x4 __attribute__((ext_vector_type(4)));
typedef float f32x16 __attribute__((ext_vector_type(16)));
typedef unsigned short ushort8_t __attribute__((ext_vector_type(8)));
typedef unsigned int uint4_t __attribute__((ext_vector_type(4)));

#define DEVI static __device__ __forceinline__

#define QSCALE 0.180336880111112f  // 0.125 * log2(e)

DEVI unsigned short f2bf(float f) {
    union { float f; unsigned int u; } c; c.f = f;
    unsigned int u = c.u;
    unsigned int r = (u + 0x7FFFu + ((u >> 16) & 1u)) >> 16;  // RNE
    return (unsigned short)r;
}

DEVI f32x4 mfma16(bf16x8 a, bf16x8 b, f32x4 c) {
    return __builtin_amdgcn_mfma_f32_16x16x32_bf16(a, b, c, 0, 0, 0);
}
DEVI f32x16 mfma32(bf16x8 a, bf16x8 b, f32x16 c) {
    return __builtin_amdgcn_mfma_f32_32x32x16_bf16(a, b, c, 0, 0, 0);
}
DEVI unsigned cvtpk(float a, float b) {
    unsigned r;
    asm("v_cvt_pk_bf16_f32 %0, %1, %2" : "=v"(r) : "v"(a), "v"(b));
    return r;
}
DEVI void plswap(unsigned& a, unsigned& b) {
    asm("v_permlane32_swap_b32 %0, %1" : "+v"(a), "+v"(b));
}
DEVI void gload16(const unsigned short* g, unsigned short* l) {
    __builtin_amdgcn_global_load_lds(
        (const __attribute__((address_space(1))) void*)g,
        (__attribute__((address_space(3))) void*)l, 16, 0, 0);
}
#define WAIT_VM(n) asm volatile("s_waitcnt vmcnt(" #n ")" ::: "memory")
#define WAIT_LGKM0() asm volatile("s_waitcnt lgkmcnt(0)" ::: "memory")
#define BAR() __builtin_amdgcn_s_barrier()

DEVI void cvt8(const float* src, unsigned short* dst) {
    float4 f0 = *(const float4*)(src);
    float4 f1 = *(const float4*)(src + 4);
    ushort8_t v;
    v[0] = f2bf(f0.x); v[1] = f2bf(f0.y); v[2] = f2bf(f0.z); v[3] = f2bf(f0.w);
    v[4] = f2bf(f1.x); v[5] = f2bf(f1.y); v[6] = f2bf(f1.z); v[7] = f2bf(f1.w);
    *(ushort8_t*)(dst) = v;
}

// blocks 0..2047: gather+cast e; 2048+: weight converts (counts in 2048-elem rows)
__global__ __launch_bounds__(256)
void prep_k(const int* __restrict__ X, const float* __restrict__ emb,
            unsigned short* __restrict__ e,
            const float* __restrict__ Wk, unsigned short* __restrict__ Wkb,
            const float* __restrict__ Wv, unsigned short* __restrict__ Wvb,
            const float* __restrict__ Wq, unsigned short* __restrict__ Wqb,
            const float* __restrict__ Wo, unsigned short* __restrict__ Wob) {
    int b = blockIdx.x;
    if (b < 2048) {
        long long row = X[b];
        cvt8(emb + row * 2048 + threadIdx.x * 8, e + (size_t)b * 2048 + threadIdx.x * 8);
        return;
    }
    b -= 2048;
    const float* s; unsigned short* d; int off;
    if (b < 512) { s = Wk; d = Wkb; off = b; }
    else if (b < 1024) { s = Wv; d = Wvb; off = b - 512; }
    else if (b < 3072) { s = Wq; d = Wqb; off = b - 1024; }
    else { s = Wo; d = Wob; off = b - 3072; }
    size_t idx = ((size_t)off * 256 + threadIdx.x) * 8;
    cvt8(s + idx, d + idx);
}

// C[m][n] = sum_k A[m][k] * W[n][k], A,W bf16 [*][2048]. 128x128 tile, BK=64,
// 2-phase dbuf global_load_lds, counted vmcnt, XOR-swizzled LDS granules.
// OM: 0 bf16; 1 f32+bias; 2 bf16 transposed; 3 bf16 scaled by QSCALE.
template<int OM0, int OM1, int OM2>
__global__ __launch_bounds__(256)
void gemm_swz_k(const unsigned short* __restrict__ A,
                const unsigned short* __restrict__ W0, const unsigned short* __restrict__ W1,
                const unsigned short* __restrict__ W2,
                void* __restrict__ C0, void* __restrict__ C1, void* __restrict__ C2,
                int t1, int t2, int ldc0, int ldc1, int ldc2,
                const float* __restrict__ bias) {
    __shared__ unsigned short As[2 * 128 * 64];
    __shared__ unsigned short Bs[2 * 128 * 64];
    const int cpx = gridDim.x >> 3;
    int id = blockIdx.x;
    int swz = (id & 7) * cpx + (id >> 3);
    const int bx = swz & 15;
    const int by = swz >> 4;
    const unsigned short* Wp; void* Cp; int ldc, om, nb;
    if (by < t1)      { Wp = W0; Cp = C0; ldc = ldc0; om = OM0; nb = by; }
    else if (by < t2) { Wp = W1; Cp = C1; ldc = ldc1; om = OM1; nb = by - t1; }
    else              { Wp = W2; Cp = C2; ldc = ldc2; om = OM2; nb = by - t2; }
    const int m0 = bx * 128, n0 = nb * 128;
    const int tid = threadIdx.x, lane = tid & 63, w = tid >> 6;
    const int wm = (w >> 1) * 64, wn = (w & 1) * 64;
    const int lr = lane & 15, lg = lane >> 4;
    const int srow = tid >> 3, sj = tid & 7;

    f32x4 acc[4][4];
    #pragma unroll
    for (int i = 0; i < 4; i++)
        #pragma unroll
        for (int j = 0; j < 4; j++) acc[i][j] = {};

    // stage: LDS dest lane-linear; global source granule pre-swizzled sj^(row&7)
    #define G_STAGE(buf, k0)                                                          \
        _Pragma("unroll")                                                             \
        for (int i = 0; i < 4; i++) {                                                 \
            int row = srow + i * 32;                                                  \
            int jj = sj ^ (row & 7);                                                  \
            unsigned short* ad = As + (buf) * 8192 + (w * 64 + i * 256) * 8;          \
            unsigned short* bd = Bs + (buf) * 8192 + (w * 64 + i * 256) * 8;          \
            gload16(A  + (size_t)(m0 + row) * 2048 + (k0) + jj * 8, ad);              \
            gload16(Wp + (size_t)(n0 + row) * 2048 + (k0) + jj * 8, bd);              \
        }

    G_STAGE(0, 0);
    for (int s = 0; s < 32; ++s) {
        const int cur = s & 1;
        if (s < 31) {
            G_STAGE(cur ^ 1, (s + 1) * 64);
            WAIT_VM(8);
        } else {
            WAIT_VM(0);
        }
        BAR();
        const unsigned short* Asb = As + cur * 8192;
        const unsigned short* Bsb = Bs + cur * 8192;
        #pragma unroll
        for (int kk = 0; kk < 2; kk++) {
            bf16x8 af[4], bfr[4];
            #pragma unroll
            for (int mi = 0; mi < 4; mi++) {
                int r = wm + mi * 16 + lr;
                int g = (kk * 4 + lg) ^ (r & 7);
                af[mi] = *(const bf16x8*)(&Asb[r * 64 + g * 8]);
            }
            #pragma unroll
            for (int ni = 0; ni < 4; ni++) {
                int r = wn + ni * 16 + lr;
                int g = (kk * 4 + lg) ^ (r & 7);
                bfr[ni] = *(const bf16x8*)(&Bsb[r * 64 + g * 8]);
            }
            __builtin_amdgcn_s_setprio(1);
            #pragma unroll
            for (int mi = 0; mi < 4; mi++)
                #pragma unroll
                for (int ni = 0; ni < 4; ni++)
                    acc[mi][ni] = mfma16(af[mi], bfr[ni], acc[mi][ni]);
            __builtin_amdgcn_s_setprio(0);
        }
        WAIT_LGKM0();
        BAR();
    }
    #undef G_STAGE

    #pragma unroll
    for (int mi = 0; mi < 4; mi++)
        #pragma unroll
        for (int ni = 0; ni < 4; ni++) {
            int col = n0 + wn + ni * 16 + lr;
            #pragma unroll
            for (int jj = 0; jj < 4; jj++) {
                int rowg = m0 + wm + mi * 16 + lg * 4 + jj;
                float vv = acc[mi][ni][jj];
                if (om == 0) {
                    ((unsigned short*)Cp)[(size_t)rowg * ldc + col] = f2bf(vv);
                } else if (om == 1) {
                    ((float*)Cp)[(size_t)rowg * ldc + col] = vv + bias[col];
                } else if (om == 2) {
                    ((unsigned short*)Cp)[(size_t)col * ldc + rowg] = f2bf(vv);
                } else {
                    ((unsigned short*)Cp)[(size_t)rowg * ldc + col] = f2bf(vv * QSCALE);
                }
            }
        }
}

// Flash attention. Grid 512 (XCD-chunked: ikv == blockIdx%8). 4 waves x 32 q-rows.
// Q pre-scaled by QSCALE => p = exp2(s - m) directly. l via MFMA ones-trick.
__global__ __launch_bounds__(256)
void attn2_k(const unsigned short* __restrict__ Qb, const unsigned short* __restrict__ Kb,
             const unsigned short* __restrict__ VbT, unsigned short* __restrict__ Ctx) {
    __shared__ unsigned short Ks[2 * 64 * 64];
    __shared__ unsigned short Vts[2 * 64 * 64];
    int id = blockIdx.x;
    int swz = (id & 7) * 64 + (id >> 3);   // XCD c owns heads 4c..4c+3 (KV L2-resident)
    const int hq = swz >> 4;
    const int qt = swz & 15;
    const int ikv = hq >> 2;
    const int tid = threadIdx.x, lane = tid & 63, w = tid >> 6;
    const int l31 = lane & 31, hi = lane >> 5;
    const int qrow = qt * 128 + w * 32 + l31;
    const int srow = tid >> 3, sj = tid & 7;

    bf16x8 qf[4];
    #pragma unroll
    for (int ks = 0; ks < 4; ks++)
        qf[ks] = *(const bf16x8*)(Qb + (size_t)qrow * 2048 + hq * 64 + ks * 16 + hi * 8);

    bf16x8 onesb;
    #pragma unroll
    for (int i = 0; i < 8; i++) onesb[i] = (__bf16)1.0f;

    f32x16 oacc0 = {}, oacc1 = {}, lacc = {};
    float m = -1e30f;

    #define A_STAGE(buf, t0)                                                          \
        _Pragma("unroll")                                                             \
        for (int i = 0; i < 2; i++) {                                                 \
            int row = srow + i * 32;                                                  \
            int jj = sj ^ (row & 7);                                                  \
            unsigned short* kd = Ks + (buf) * 4096 + (w * 64 + i * 256) * 8;          \
            unsigned short* vd = Vts + (buf) * 4096 + (w * 64 + i * 256) * 8;         \
            gload16(Kb + (size_t)((t0) + row) * 512 + ikv * 64 + jj * 8, kd);         \
            gload16(VbT + (size_t)(ikv * 64 + row) * 2048 + (t0) + jj * 8, vd);       \
        }

    A_STAGE(0, 0);
    for (int t = 0; t < 32; ++t) {
        const int cur = t & 1;
        if (t < 31) {
            A_STAGE(cur ^ 1, (t + 1) * 64);
            WAIT_VM(4);
        } else {
            WAIT_VM(0);
        }
        BAR();
        const unsigned short* Ksb = Ks + cur * 4096;
        const unsigned short* Vsb = Vts + cur * 4096;

        // S^T = K Q^T (pre-scaled Q: s is already in log2 softmax domain)
        f32x16 s0 = {}, s1 = {};
        __builtin_amdgcn_s_setprio(1);
        #pragma unroll
        for (int ks = 0; ks < 4; ks++) {
            int gr = (2 * ks + hi) ^ (l31 & 7);
            bf16x8 kf0 = *(const bf16x8*)(&Ksb[l31 * 64 + gr * 8]);
            bf16x8 kf1 = *(const bf16x8*)(&Ksb[(32 + l31) * 64 + gr * 8]);
            s0 = mfma32(kf0, qf[ks], s0);
            s1 = mfma32(kf1, qf[ks], s1);
        }
        __builtin_amdgcn_s_setprio(0);

        // max via max3 triples (lane owns q-row l31; kt over 32 regs + partner lane)
        float a0 = fmaxf(fmaxf(s0[0],  s0[1]),  s0[2]);
        float a1 = fmaxf(fmaxf(s0[3],  s0[4]),  s0[5]);
        float a2 = fmaxf(fmaxf(s0[6],  s0[7]),  s0[8]);
        float a3 = fmaxf(fmaxf(s0[9],  s0[10]), s0[11]);
        float a4 = fmaxf(fmaxf(s0[12], s0[13]), s0[14]);
        float b0 = fmaxf(fmaxf(s1[0],  s1[1]),  s1[2]);
        float b1 = fmaxf(fmaxf(s1[3],  s1[4]),  s1[5]);
        float b2 = fmaxf(fmaxf(s1[6],  s1[7]),  s1[8]);
        float b3 = fmaxf(fmaxf(s1[9],  s1[10]), s1[11]);
        float b4 = fmaxf(fmaxf(s1[12], s1[13]), s1[14]);
        float c0 = fmaxf(s0[15], s1[15]);
        float d0 = fmaxf(fmaxf(a0, a1), a2);
        float d1 = fmaxf(fmaxf(a3, a4), b0);
        float d2 = fmaxf(fmaxf(b1, b2), b3);
        float d3 = fmaxf(fmaxf(b4, c0), d0);
        float pmax = fmaxf(fmaxf(d1, d2), d3);
        pmax = fmaxf(pmax, __shfl_xor(pmax, 32, 64));

        if (!__all(pmax <= m + 8.0f)) {
            float mnew = fmaxf(m, pmax);
            float sc = exp2f(m - mnew);
            m = mnew;
            #pragma unroll
            for (int r = 0; r < 16; r++) {
                const int qp = (r & 3) + 8 * (r >> 2);
                float scv = __shfl(sc, qp + 4 * hi, 64);
                oacc0[r] *= scv;
                oacc1[r] *= scv;
                lacc[r] *= scv;
            }
        }

        #pragma unroll
        for (int r = 0; r < 16; r++) {
            s0[r] = exp2f(s0[r] - m);
            s1[r] = exp2f(s1[r] - m);
        }

        // pack P -> A-fragments (cvt_pk + permlane32_swap)
        uint4_t pw[4];
        #pragma unroll
        for (int c = 0; c < 2; c++) {
            unsigned a   = cvtpk(s0[8 * c + 0], s0[8 * c + 1]);
            unsigned bb  = cvtpk(s0[8 * c + 2], s0[8 * c + 3]);
            unsigned cc2 = cvtpk(s0[8 * c + 4], s0[8 * c + 5]);
            unsigned dd  = cvtpk(s0[8 * c + 6], s0[8 * c + 7]);
            plswap(a, cc2); plswap(bb, dd);
            pw[c][0] = a; pw[c][1] = bb; pw[c][2] = cc2; pw[c][3] = dd;
        }
        #pragma unroll
        for (int c = 0; c < 2; c++) {
            unsigned a   = cvtpk(s1[8 * c + 0], s1[8 * c + 1]);
            unsigned bb  = cvtpk(s1[8 * c + 2], s1[8 * c + 3]);
            unsigned cc2 = cvtpk(s1[8 * c + 4], s1[8 * c + 5]);
            unsigned dd  = cvtpk(s1[8 * c + 6], s1[8 * c + 7]);
            plswap(a, cc2); plswap(bb, dd);
            pw[2 + c][0] = a; pw[2 + c][1] = bb; pw[2 + c][2] = cc2; pw[2 + c][3] = dd;
        }

        // PV + l-row (ones-trick): lacc = P . 1 in the same reg layout as oacc
        __builtin_amdgcn_s_setprio(1);
        #pragma unroll
        for (int ks = 0; ks < 4; ks++) {
            bf16x8 pa = __builtin_bit_cast(bf16x8, pw[ks]);
            int gr = (2 * ks + hi) ^ (l31 & 7);
            bf16x8 vf0 = *(const bf16x8*)(&Vsb[l31 * 64 + gr * 8]);
            bf16x8 vf1 = *(const bf16x8*)(&Vsb[(32 + l31) * 64 + gr * 8]);
            oacc0 = mfma32(pa, vf0, oacc0);
            oacc1 = mfma32(pa, vf1, oacc1);
            lacc  = mfma32(pa, onesb, lacc);
        }
        __builtin_amdgcn_s_setprio(0);
        WAIT_LGKM0();
        BAR();
    }
    #undef A_STAGE

    #pragma unroll
    for (int r = 0; r < 16; r++) {
        float lv = 1.0f / lacc[r];
        int row = qt * 128 + w * 32 + (r & 3) + 8 * (r >> 2) + 4 * hi;
        Ctx[(size_t)row * 2048 + hq * 64 + l31]      = f2bf(oacc0[r] * lv);
        Ctx[(size_t)row * 2048 + hq * 64 + 32 + l31] = f2bf(oacc1[r] * lv);
    }
}

extern "C" void kernel_launch(void* const* d_in, const int* in_sizes, int n_in,
                              void* d_out, int out_size, void* d_ws, size_t ws_size,
                              hipStream_t stream) {
    (void)in_sizes; (void)n_in; (void)out_size; (void)ws_size;
    const int*   X   = (const int*)d_in[0];
    const float* emb = (const float*)d_in[1];
    const float* Wk  = (const float*)d_in[2];
    const float* Wv  = (const float*)d_in[3];
    const float* Wq  = (const float*)d_in[4];
    const float* Wo  = (const float*)d_in[5];
    const float* Wb  = (const float*)d_in[6];

    unsigned short* e   = (unsigned short*)d_ws;
    unsigned short* Kb  = e   + (size_t)2048 * 2048;
    unsigned short* VbT = Kb  + (size_t)2048 * 512;
    unsigned short* Qb  = VbT + (size_t)512 * 2048;
    unsigned short* Ctx = Qb  + (size_t)2048 * 2048;
    unsigned short* Wkb = Ctx + (size_t)2048 * 2048;
    unsigned short* Wvb = Wkb + (size_t)512 * 2048;
    unsigned short* Wqb = Wvb + (size_t)512 * 2048;
    unsigned short* Wob = Wqb + (size_t)2048 * 2048;

    prep_k<<<dim3(2048 + 5120), dim3(256), 0, stream>>>(X, emb, e, Wk, Wkb, Wv, Wvb,
                                                        Wq, Wqb, Wo, Wob);
    // fused QKV: by<16 Wq->Qb (scaled); by<20 Wk->Kb; else Wv->VbT (transposed)
    gemm_swz_k<3, 0, 2><<<dim3(384), dim3(256), 0, stream>>>(
        e, Wqb, Wkb, Wvb, (void*)Qb, (void*)Kb, (void*)VbT,
        16, 20, 2048, 512, 2048, nullptr);
    attn2_k<<<dim3(512), dim3(256), 0, stream>>>(Qb, Kb, VbT, Ctx);
    gemm_swz_k<1, 1, 1><<<dim3(256), dim3(256), 0, stream>>>(
        Ctx, Wob, Wob, Wob, d_out, d_out, d_out,
        16, 32, 2048, 2048, 2048, Wb);
}